// Round 11
// baseline (164.393 us; speedup 1.0000x reference)
//
#include <hip/hip_runtime.h>

#define N_NODES 50000
#define E_EDGES 600000
#define D_IN 128
#define O_OUT 128
#define R_REL 8
#define B_BAS 4
#define KTOT 640                  // 4 basis * 128 + self-loop 128
#define NSEG (N_NODES * R_REL)
#define NB1 98                    // ceil(50000/512): scan blocks == coarse buckets
#define YSTRIDE 512               // y row: 4 basis * 128

// prep kernel block ranges
#define NB_CONV 6250              // N*D/1024
#define NB_WT 320                 // 128*640/256
#define NB_DEG 2344               // ceil(E/256)

// binning
#define CHUNK_A 2048
#define NBA 293                   // ceil(600000/2048)

// gemm2: 32-row x 64-col tile per wave; 2 col-halves per row-group
#define NROWG 1563                // ceil(50000/32)
#define NWAVE (NROWG * 2)         // 3126
#define NB_G2 ((NWAVE + 3) / 4)   // 782 blocks of 4 waves

typedef __attribute__((ext_vector_type(8))) short bf16x8;
typedef __attribute__((ext_vector_type(4))) short bf16x4;
typedef __attribute__((ext_vector_type(4))) float f32x4;

static __device__ __forceinline__ unsigned short f2bf(float f) {
    unsigned int u = __float_as_uint(f);
    unsigned int r = (u + 0x7fffu + ((u >> 16) & 1u)) >> 16;
    return (unsigned short)r;
}
static __device__ __forceinline__ float bf2f(unsigned short b) {
    return __uint_as_float(((unsigned int)b) << 16);
}

// Fused: x->bf16 convert | Wt2 build | per-(dst,rel) degree count
__global__ __launch_bounds__(256) void prep_kernel(const float* __restrict__ x,
                                                   unsigned short* __restrict__ xb,
                                                   const float* __restrict__ basis_v,
                                                   const float* __restrict__ w_loop,
                                                   unsigned short* __restrict__ Wt2,
                                                   const int* __restrict__ dst,
                                                   const int* __restrict__ rel,
                                                   int* __restrict__ deg) {
    int b = blockIdx.x;
    if (b < NB_CONV) {
        int i = (b * 256 + threadIdx.x) * 4;
        float4 v = *(const float4*)&x[i];
        ushort4 o;
        o.x = f2bf(v.x); o.y = f2bf(v.y); o.z = f2bf(v.z); o.w = f2bf(v.w);
        *(ushort4*)&xb[i] = o;
    } else if (b < NB_CONV + NB_WT) {
        int i = (b - NB_CONV) * 256 + threadIdx.x;  // over 128*640
        int o = i / KTOT, j = i - o * KTOT;
        int bb = j >> 7, d = j & 127;
        float v = (bb < B_BAS) ? basis_v[((size_t)bb * D_IN + d) * O_OUT + o]
                               : w_loop[d * O_OUT + o];
        Wt2[i] = f2bf(v);
    } else {
        int e = (b - NB_CONV - NB_WT) * 256 + threadIdx.x;
        if (e < E_EDGES) atomicAdd(&deg[dst[e] * R_REL + rel[e]], 1);
    }
}

// Per-dst total count + block-local exclusive scan; emits invf too
__global__ __launch_bounds__(512) void scan1_kernel(const int* __restrict__ deg,
                                                    int* __restrict__ cntd,
                                                    float* __restrict__ invf,
                                                    int* __restrict__ exoff,
                                                    int* __restrict__ bsum) {
    __shared__ int s[512];
    int t = threadIdx.x, i = blockIdx.x * 512 + t;
    int c = 0;
    if (i < N_NODES) {
        #pragma unroll
        for (int r = 0; r < R_REL; ++r) {
            int dg = deg[i * R_REL + r];
            c += dg;
            invf[i * R_REL + r] = 1.0f / (float)max(dg, 1);
        }
        cntd[i] = c;
    }
    s[t] = c;
    __syncthreads();
    #pragma unroll
    for (int off = 1; off < 512; off <<= 1) {
        int add = (t >= off) ? s[t - off] : 0;
        __syncthreads();
        s[t] += add;
        __syncthreads();
    }
    if (i < N_NODES) exoff[i] = s[t] - c;
    if (t == 511) bsum[blockIdx.x] = s[511];
}

// Scan 98 block sums -> bbase[0..98] (with total at [98]); init cursor98 copy
__global__ __launch_bounds__(128) void scan2_kernel(const int* __restrict__ bsum,
                                                    int* __restrict__ bbase,
                                                    int* __restrict__ cursor98) {
    __shared__ int s[128];
    int t = threadIdx.x;
    int c = (t < NB1) ? bsum[t] : 0;
    s[t] = c;
    __syncthreads();
    #pragma unroll
    for (int off = 1; off < 128; off <<= 1) {
        int add = (t >= off) ? s[t - off] : 0;
        __syncthreads();
        s[t] += add;
        __syncthreads();
    }
    if (t < NB1) {
        int v = s[t] - c;
        bbase[t] = v;
        cursor98[t] = v;
    }
    if (t == NB1 - 1) bbase[NB1] = s[t];
}

// Pass A: bin edges into 98 coarse buckets (512 dsts each), block-contiguous runs.
// coarse payload: src(16) | rel(3)<<16 | dlow(9)<<19
__global__ __launch_bounds__(256) void binA_kernel(const int* __restrict__ src,
                                                   const int* __restrict__ dst,
                                                   const int* __restrict__ rel,
                                                   int* __restrict__ cursor98,
                                                   unsigned* __restrict__ coarse) {
    __shared__ int hist[NB1];
    __shared__ int base[NB1];
    int t = threadIdx.x;
    if (t < NB1) hist[t] = 0;
    __syncthreads();
    int e0 = blockIdx.x * CHUNK_A;
    for (int i = t; i < CHUNK_A; i += 256) {
        int e = e0 + i;
        if (e < E_EDGES) atomicAdd(&hist[dst[e] >> 9], 1);
    }
    __syncthreads();
    if (t < NB1) {
        int h = hist[t];
        base[t] = h ? atomicAdd(&cursor98[t], h) : 0;
        hist[t] = 0;
    }
    __syncthreads();
    for (int i = t; i < CHUNK_A; i += 256) {
        int e = e0 + i;
        if (e < E_EDGES) {
            int d = dst[e], b = d >> 9;
            int pos = base[b] + atomicAdd(&hist[b], 1);
            coarse[pos] = (unsigned)src[e] | ((unsigned)rel[e] << 16)
                        | ((unsigned)(d & 511) << 19);
        }
    }
}

// Pass B: one block per coarse bucket; exact per-dst slots via LDS counters.
__global__ __launch_bounds__(512) void binB_kernel(const unsigned* __restrict__ coarse,
                                                   const int* __restrict__ bbase,
                                                   const int* __restrict__ exoff,
                                                   unsigned* __restrict__ epack) {
    __shared__ int lcnt[512];
    int b = blockIdx.x, t = threadIdx.x;
    int d0 = b << 9;
    lcnt[t] = (d0 + t < N_NODES) ? exoff[d0 + t] : 0;
    __syncthreads();
    int s0 = bbase[b], s1 = bbase[b + 1];
    for (int i = s0 + t; i < s1; i += 512) {
        unsigned p = coarse[i];
        int dlow = (p >> 19) & 511;
        int pos = s0 + atomicAdd(&lcnt[dlow], 1);
        epack[pos] = p & 0x7ffffu;  // src | rel<<16
    }
}

// segagg: 32 lanes per dst node; 4-deep pipelined edge walk.
// y[d][b*128+..] = sum_edges coeffs[rel,b]*inv_deg*x_src
__global__ __launch_bounds__(256) void segagg_kernel(const unsigned short* __restrict__ xb,
                                                     const int* __restrict__ exoff,
                                                     const int* __restrict__ bbase,
                                                     const int* __restrict__ cntd,
                                                     const float* __restrict__ invf,
                                                     const unsigned* __restrict__ epack,
                                                     const float* __restrict__ coeffs,
                                                     unsigned short* __restrict__ y) {
    int d = blockIdx.x * 8 + (threadIdx.x >> 5);  // grid exact: 50000/8
    int l = threadIdx.x & 31;
    int beg = exoff[d] + bbase[d >> 9];
    int n = cntd[d];
    const unsigned* ep = epack + beg;
    float a0[4] = {}, a1[4] = {}, a2[4] = {}, a3[4] = {};
    int k = 0;
    for (; k + 4 <= n; k += 4) {
        unsigned p0 = ep[k], p1 = ep[k + 1], p2 = ep[k + 2], p3 = ep[k + 3];
        int s0 = p0 & 0xffffu, r0 = p0 >> 16;
        int s1 = p1 & 0xffffu, r1 = p1 >> 16;
        int s2 = p2 & 0xffffu, r2 = p2 >> 16;
        int s3 = p3 & 0xffffu, r3 = p3 >> 16;
        bf16x4 v0 = *(const bf16x4*)&xb[(size_t)s0 * D_IN + l * 4];
        bf16x4 v1 = *(const bf16x4*)&xb[(size_t)s1 * D_IN + l * 4];
        bf16x4 v2 = *(const bf16x4*)&xb[(size_t)s2 * D_IN + l * 4];
        bf16x4 v3 = *(const bf16x4*)&xb[(size_t)s3 * D_IN + l * 4];
        float i0 = invf[d * R_REL + r0];
        float i1 = invf[d * R_REL + r1];
        float i2 = invf[d * R_REL + r2];
        float i3 = invf[d * R_REL + r3];
        float4 cA = *(const float4*)&coeffs[r0 * B_BAS];
        float4 cB = *(const float4*)&coeffs[r1 * B_BAS];
        float4 cC = *(const float4*)&coeffs[r2 * B_BAS];
        float4 cD = *(const float4*)&coeffs[r3 * B_BAS];
        cA.x *= i0; cA.y *= i0; cA.z *= i0; cA.w *= i0;
        cB.x *= i1; cB.y *= i1; cB.z *= i1; cB.w *= i1;
        cC.x *= i2; cC.y *= i2; cC.z *= i2; cC.w *= i2;
        cD.x *= i3; cD.y *= i3; cD.z *= i3; cD.w *= i3;
        #pragma unroll
        for (int j = 0; j < 4; ++j) {
            float x0 = bf2f((unsigned short)v0[j]);
            float x1 = bf2f((unsigned short)v1[j]);
            float x2 = bf2f((unsigned short)v2[j]);
            float x3 = bf2f((unsigned short)v3[j]);
            a0[j] += cA.x * x0; a1[j] += cA.y * x0;
            a2[j] += cA.z * x0; a3[j] += cA.w * x0;
            a0[j] += cB.x * x1; a1[j] += cB.y * x1;
            a2[j] += cB.z * x1; a3[j] += cB.w * x1;
            a0[j] += cC.x * x2; a1[j] += cC.y * x2;
            a2[j] += cC.z * x2; a3[j] += cC.w * x2;
            a0[j] += cD.x * x3; a1[j] += cD.y * x3;
            a2[j] += cD.z * x3; a3[j] += cD.w * x3;
        }
    }
    for (; k < n; ++k) {
        unsigned p0 = ep[k];
        int s0 = p0 & 0xffffu, r0 = p0 >> 16;
        bf16x4 v0 = *(const bf16x4*)&xb[(size_t)s0 * D_IN + l * 4];
        float i0 = invf[d * R_REL + r0];
        float4 cA = *(const float4*)&coeffs[r0 * B_BAS];
        cA.x *= i0; cA.y *= i0; cA.z *= i0; cA.w *= i0;
        #pragma unroll
        for (int j = 0; j < 4; ++j) {
            float x0 = bf2f((unsigned short)v0[j]);
            a0[j] += cA.x * x0; a1[j] += cA.y * x0;
            a2[j] += cA.z * x0; a3[j] += cA.w * x0;
        }
    }
    size_t base = (size_t)d * YSTRIDE + l * 4;
    #pragma unroll
    for (int b = 0; b < 4; ++b) {
        const float* ab = (b == 0) ? a0 : (b == 1) ? a1 : (b == 2) ? a2 : a3;
        ushort4 o;
        o.x = f2bf(ab[0]); o.y = f2bf(ab[1]); o.z = f2bf(ab[2]); o.w = f2bf(ab[3]);
        *(ushort4*)&y[base + b * 128] = o;
    }
}

// gemm2: out = relu([y | xb] @ [Vstack; w_loop] + bias), K=640.
// Barrier-free, LDS-free: each wave owns a 32-row x 64-col tile; A fragments
// loaded directly global->VGPR (16 rows x 64 B per k-step, coalesced);
// B fragments direct from L2-resident Wt2 (160 KB).
__global__ __launch_bounds__(256) void gemm2_kernel(const unsigned short* __restrict__ y,
                                                    const unsigned short* __restrict__ xb,
                                                    const unsigned short* __restrict__ Wt2,
                                                    const float* __restrict__ bias,
                                                    float* __restrict__ out) {
    const int t = threadIdx.x;
    const int w = t >> 6, l = t & 63;
    const int wid = blockIdx.x * 4 + w;
    const int rowg = wid >> 1, colh = wid & 1;
    if (rowg >= NROWG) return;
    const int m0 = rowg * 32;
    const int c0 = colh * 64;
    const int lr = l & 15, lg = l >> 4;

    int arow0 = m0 + lr;
    int arow1 = m0 + 16 + lr;
    if (arow0 >= N_NODES) arow0 = N_NODES - 1;  // clamp; stores guarded below
    if (arow1 >= N_NODES) arow1 = N_NODES - 1;

    f32x4 acc[2][4] = {};

    #pragma unroll
    for (int r = 0; r < 5; ++r) {
        const unsigned short* A0;
        const unsigned short* A1;
        if (r < B_BAS) {
            A0 = y + (size_t)arow0 * YSTRIDE + r * 128;
            A1 = y + (size_t)arow1 * YSTRIDE + r * 128;
        } else {
            A0 = xb + (size_t)arow0 * D_IN;
            A1 = xb + (size_t)arow1 * D_IN;
        }
        #pragma unroll
        for (int ks = 0; ks < 4; ++ks) {
            int kb = ks * 32 + lg * 8;
            bf16x8 a0 = *(const bf16x8*)&A0[kb];
            bf16x8 a1 = *(const bf16x8*)&A1[kb];
            #pragma unroll
            for (int jn = 0; jn < 4; ++jn) {
                bf16x8 bfr = *(const bf16x8*)&Wt2[(size_t)(c0 + jn * 16 + lr) * KTOT + r * 128 + kb];
                acc[0][jn] = __builtin_amdgcn_mfma_f32_16x16x32_bf16(a0, bfr, acc[0][jn], 0, 0, 0);
                acc[1][jn] = __builtin_amdgcn_mfma_f32_16x16x32_bf16(a1, bfr, acc[1][jn], 0, 0, 0);
            }
        }
    }

    // epilogue: C/D layout col=lane&15, row=(lane>>4)*4+i  [m89-verified]
    #pragma unroll
    for (int jn = 0; jn < 4; ++jn) {
        int col = c0 + jn * 16 + lr;
        float bv = bias[col];
        #pragma unroll
        for (int im = 0; im < 2; ++im) {
            #pragma unroll
            for (int i2 = 0; i2 < 4; ++i2) {
                int row = m0 + im * 16 + lg * 4 + i2;
                if (row < N_NODES)
                    out[(size_t)row * O_OUT + col] = fmaxf(acc[im][jn][i2] + bv, 0.f);
            }
        }
    }
}

extern "C" void kernel_launch(void* const* d_in, const int* in_sizes, int n_in,
                              void* d_out, int out_size, void* d_ws, size_t ws_size,
                              hipStream_t stream) {
    (void)in_sizes; (void)n_in; (void)out_size; (void)ws_size;
    const float* x       = (const float*)d_in[0];
    const float* basis_v = (const float*)d_in[1];
    const float* coeffs  = (const float*)d_in[2];
    const float* w_loop  = (const float*)d_in[3];
    const float* bias_p  = (const float*)d_in[4];
    const int*   src     = (const int*)d_in[5];
    const int*   dst     = (const int*)d_in[6];
    const int*   rel     = (const int*)d_in[7];
    float* out = (float*)d_out;

    char* ws = (char*)d_ws;
    unsigned short* Wt2      = (unsigned short*)(ws);             //     163,840 B
    unsigned short* xb       = (unsigned short*)(ws + 163840);    //  12,800,000 B
    int*            deg      = (int*)(ws + 12963840);             //   1,600,000 B
    float*          invf     = (float*)(ws + 14563840);           //   1,600,000 B
    int*            cntd     = (int*)(ws + 16163840);             //     200,000 B
    int*            exoff    = (int*)(ws + 16363840);             //     200,000 B
    int*            bsum     = (int*)(ws + 16563840);             //       1,024 B
    int*            bbase    = (int*)(ws + 16564864);             //       1,024 B (99 ints)
    int*            cursor98 = (int*)(ws + 16565888);             //       1,024 B
    unsigned*       coarse   = (unsigned*)(ws + 16566912);        //   2,400,000 B
    unsigned*       epack    = (unsigned*)(ws + 18966912);        //   2,400,000 B
    unsigned short* y        = (unsigned short*)(ws + 21366912);  //  51,200,000 B

    hipMemsetAsync(deg, 0, (size_t)NSEG * sizeof(int), stream);

    prep_kernel<<<NB_CONV + NB_WT + NB_DEG, 256, 0, stream>>>(x, xb, basis_v, w_loop, Wt2,
                                                              dst, rel, deg);
    scan1_kernel<<<NB1, 512, 0, stream>>>(deg, cntd, invf, exoff, bsum);
    scan2_kernel<<<1, 128, 0, stream>>>(bsum, bbase, cursor98);
    binA_kernel<<<NBA, 256, 0, stream>>>(src, dst, rel, cursor98, coarse);
    binB_kernel<<<NB1, 512, 0, stream>>>(coarse, bbase, exoff, epack);
    segagg_kernel<<<N_NODES / 8, 256, 0, stream>>>(xb, exoff, bbase, cntd, invf, epack,
                                                   coeffs, y);
    gemm2_kernel<<<NB_G2, 256, 0, stream>>>(y, xb, Wt2, bias_p, out);
}

// Round 12
// 155.918 us; speedup vs baseline: 1.0544x; 1.0544x over previous
//
#include <hip/hip_runtime.h>

#define N_NODES 50000
#define E_EDGES 600000
#define D_IN 128
#define O_OUT 128
#define R_REL 8
#define B_BAS 4
#define KTOT 640                  // 4 basis * 128 + self-loop 128
#define NSEG (N_NODES * R_REL)
#define NB1 98                    // ceil(50000/512): scan blocks == coarse buckets
#define NRT 3125                  // 50000 / 16 row tiles (exact)
#define NKC 20                    // 640 / 32 k-chunks

// prep kernel block ranges
#define NB_CONV 6250              // N*D/1024
#define NB_WT 320                 // 128*640/256
#define NB_DEG 2344               // ceil(E/256)

// binning
#define CHUNK_A 2048
#define NBA 293                   // ceil(600000/2048)

typedef __attribute__((ext_vector_type(8))) short bf16x8;
typedef __attribute__((ext_vector_type(4))) short bf16x4;
typedef __attribute__((ext_vector_type(4))) float f32x4;

static __device__ __forceinline__ unsigned short f2bf(float f) {
    unsigned int u = __float_as_uint(f);
    unsigned int r = (u + 0x7fffu + ((u >> 16) & 1u)) >> 16;
    return (unsigned short)r;
}
static __device__ __forceinline__ float bf2f(unsigned short b) {
    return __uint_as_float(((unsigned int)b) << 16);
}

// zero the deg table (replaces hipMemsetAsync; NSEG ints = 100000 int4)
__global__ void zero_kernel(int4* __restrict__ deg4) {
    int i = blockIdx.x * 256 + threadIdx.x;
    if (i < NSEG / 4) deg4[i] = make_int4(0, 0, 0, 0);
}

// Fused: x->bf16 convert | Wt2f (fragment-layout weights) | per-(dst,rel) degree
// Wt2f[ct][kc][lane][j] = W[k][ct*16+(lane&15)], k = kc*32+(lane>>4)*8+j
//   (k<512: basis chunk r=k>>7; k>=512: w_loop)
__global__ __launch_bounds__(256) void prep_kernel(const float* __restrict__ x,
                                                   unsigned short* __restrict__ xb,
                                                   const float* __restrict__ basis_v,
                                                   const float* __restrict__ w_loop,
                                                   unsigned short* __restrict__ Wt2f,
                                                   const int* __restrict__ dst,
                                                   const int* __restrict__ rel,
                                                   int* __restrict__ deg) {
    int b = blockIdx.x;
    if (b < NB_CONV) {
        int i = (b * 256 + threadIdx.x) * 4;
        float4 v = *(const float4*)&x[i];
        ushort4 o;
        o.x = f2bf(v.x); o.y = f2bf(v.y); o.z = f2bf(v.z); o.w = f2bf(v.w);
        *(ushort4*)&xb[i] = o;
    } else if (b < NB_CONV + NB_WT) {
        int i = (b - NB_CONV) * 256 + threadIdx.x;  // over 8*20*64*8 = 81920
        int j = i & 7, l = (i >> 3) & 63, rest = i >> 9;
        int kc = rest % NKC, ct = rest / NKC;
        int col = ct * 16 + (l & 15);
        int k = kc * 32 + (l >> 4) * 8 + j;
        int r = k >> 7, d = k & 127;
        float v = (r < B_BAS) ? basis_v[((size_t)r * D_IN + d) * O_OUT + col]
                              : w_loop[(size_t)d * O_OUT + col];
        Wt2f[i] = f2bf(v);
    } else {
        int e = (b - NB_CONV - NB_WT) * 256 + threadIdx.x;
        if (e < E_EDGES) atomicAdd(&deg[dst[e] * R_REL + rel[e]], 1);
    }
}

// Per-dst total count + block-local exclusive scan; emits invf too
__global__ __launch_bounds__(512) void scan1_kernel(const int* __restrict__ deg,
                                                    int* __restrict__ cntd,
                                                    float* __restrict__ invf,
                                                    int* __restrict__ exoff,
                                                    int* __restrict__ bsum) {
    __shared__ int s[512];
    int t = threadIdx.x, i = blockIdx.x * 512 + t;
    int c = 0;
    if (i < N_NODES) {
        #pragma unroll
        for (int r = 0; r < R_REL; ++r) {
            int dg = deg[i * R_REL + r];
            c += dg;
            invf[i * R_REL + r] = 1.0f / (float)max(dg, 1);
        }
        cntd[i] = c;
    }
    s[t] = c;
    __syncthreads();
    #pragma unroll
    for (int off = 1; off < 512; off <<= 1) {
        int add = (t >= off) ? s[t - off] : 0;
        __syncthreads();
        s[t] += add;
        __syncthreads();
    }
    if (i < N_NODES) exoff[i] = s[t] - c;
    if (t == 511) bsum[blockIdx.x] = s[511];
}

// Scan 98 block sums -> bbase[0..98]; init cursor98 copy
__global__ __launch_bounds__(128) void scan2_kernel(const int* __restrict__ bsum,
                                                    int* __restrict__ bbase,
                                                    int* __restrict__ cursor98) {
    __shared__ int s[128];
    int t = threadIdx.x;
    int c = (t < NB1) ? bsum[t] : 0;
    s[t] = c;
    __syncthreads();
    #pragma unroll
    for (int off = 1; off < 128; off <<= 1) {
        int add = (t >= off) ? s[t - off] : 0;
        __syncthreads();
        s[t] += add;
        __syncthreads();
    }
    if (t < NB1) {
        int v = s[t] - c;
        bbase[t] = v;
        cursor98[t] = v;
    }
    if (t == NB1 - 1) bbase[NB1] = s[t];
}

// Pass A: bin edges into 98 coarse buckets (512 dsts each), block-contiguous runs.
// coarse payload: src(16) | rel(3)<<16 | dlow(9)<<19
__global__ __launch_bounds__(256) void binA_kernel(const int* __restrict__ src,
                                                   const int* __restrict__ dst,
                                                   const int* __restrict__ rel,
                                                   int* __restrict__ cursor98,
                                                   unsigned* __restrict__ coarse) {
    __shared__ int hist[NB1];
    __shared__ int base[NB1];
    int t = threadIdx.x;
    if (t < NB1) hist[t] = 0;
    __syncthreads();
    int e0 = blockIdx.x * CHUNK_A;
    for (int i = t; i < CHUNK_A; i += 256) {
        int e = e0 + i;
        if (e < E_EDGES) atomicAdd(&hist[dst[e] >> 9], 1);
    }
    __syncthreads();
    if (t < NB1) {
        int h = hist[t];
        base[t] = h ? atomicAdd(&cursor98[t], h) : 0;
        hist[t] = 0;
    }
    __syncthreads();
    for (int i = t; i < CHUNK_A; i += 256) {
        int e = e0 + i;
        if (e < E_EDGES) {
            int d = dst[e], b = d >> 9;
            int pos = base[b] + atomicAdd(&hist[b], 1);
            coarse[pos] = (unsigned)src[e] | ((unsigned)rel[e] << 16)
                        | ((unsigned)(d & 511) << 19);
        }
    }
}

// Pass B: one block per coarse bucket; exact per-dst slots via LDS counters.
__global__ __launch_bounds__(512) void binB_kernel(const unsigned* __restrict__ coarse,
                                                   const int* __restrict__ bbase,
                                                   const int* __restrict__ exoff,
                                                   unsigned* __restrict__ epack) {
    __shared__ int lcnt[512];
    int b = blockIdx.x, t = threadIdx.x;
    int d0 = b << 9;
    lcnt[t] = (d0 + t < N_NODES) ? exoff[d0 + t] : 0;
    __syncthreads();
    int s0 = bbase[b], s1 = bbase[b + 1];
    for (int i = s0 + t; i < s1; i += 512) {
        unsigned p = coarse[i];
        int dlow = (p >> 19) & 511;
        int pos = s0 + atomicAdd(&lcnt[dlow], 1);
        epack[pos] = p & 0x7ffffu;  // src | rel<<16
    }
}

// segagg: 32 lanes per dst node; 4-deep pipelined edge walk.
// Writes yfrag in MFMA fragment order:
//   yfrag[((rt*20 + kc)*64 + lhi*16 + lrow)*8 + j] = A[d][k],
//   rt=d>>4, lrow=d&15, kc=k>>5, lhi=(k>>3)&3, j=k&7.
// Lane l holds k = b*128 + l*4 + m  ->  kc=b*4+(l>>3), lhi=(l>>1)&3, j=(l&1)*4+m.
// Chunks kc=16..19 are the self-loop xb row (k = 512 + l*4 + m).
__global__ __launch_bounds__(256) void segagg_kernel(const unsigned short* __restrict__ xb,
                                                     const int* __restrict__ exoff,
                                                     const int* __restrict__ bbase,
                                                     const int* __restrict__ cntd,
                                                     const float* __restrict__ invf,
                                                     const unsigned* __restrict__ epack,
                                                     const float* __restrict__ coeffs,
                                                     unsigned short* __restrict__ yfrag) {
    int d = blockIdx.x * 8 + (threadIdx.x >> 5);  // grid exact: 50000/8
    int l = threadIdx.x & 31;
    int beg = exoff[d] + bbase[d >> 9];
    int n = cntd[d];
    const unsigned* ep = epack + beg;
    float a0[4] = {}, a1[4] = {}, a2[4] = {}, a3[4] = {};
    int k = 0;
    for (; k + 4 <= n; k += 4) {
        unsigned p0 = ep[k], p1 = ep[k + 1], p2 = ep[k + 2], p3 = ep[k + 3];
        int s0 = p0 & 0xffffu, r0 = p0 >> 16;
        int s1 = p1 & 0xffffu, r1 = p1 >> 16;
        int s2 = p2 & 0xffffu, r2 = p2 >> 16;
        int s3 = p3 & 0xffffu, r3 = p3 >> 16;
        bf16x4 v0 = *(const bf16x4*)&xb[(size_t)s0 * D_IN + l * 4];
        bf16x4 v1 = *(const bf16x4*)&xb[(size_t)s1 * D_IN + l * 4];
        bf16x4 v2 = *(const bf16x4*)&xb[(size_t)s2 * D_IN + l * 4];
        bf16x4 v3 = *(const bf16x4*)&xb[(size_t)s3 * D_IN + l * 4];
        float i0 = invf[d * R_REL + r0];
        float i1 = invf[d * R_REL + r1];
        float i2 = invf[d * R_REL + r2];
        float i3 = invf[d * R_REL + r3];
        float4 cA = *(const float4*)&coeffs[r0 * B_BAS];
        float4 cB = *(const float4*)&coeffs[r1 * B_BAS];
        float4 cC = *(const float4*)&coeffs[r2 * B_BAS];
        float4 cD = *(const float4*)&coeffs[r3 * B_BAS];
        cA.x *= i0; cA.y *= i0; cA.z *= i0; cA.w *= i0;
        cB.x *= i1; cB.y *= i1; cB.z *= i1; cB.w *= i1;
        cC.x *= i2; cC.y *= i2; cC.z *= i2; cC.w *= i2;
        cD.x *= i3; cD.y *= i3; cD.z *= i3; cD.w *= i3;
        #pragma unroll
        for (int j = 0; j < 4; ++j) {
            float x0 = bf2f((unsigned short)v0[j]);
            float x1 = bf2f((unsigned short)v1[j]);
            float x2 = bf2f((unsigned short)v2[j]);
            float x3 = bf2f((unsigned short)v3[j]);
            a0[j] += cA.x * x0; a1[j] += cA.y * x0;
            a2[j] += cA.z * x0; a3[j] += cA.w * x0;
            a0[j] += cB.x * x1; a1[j] += cB.y * x1;
            a2[j] += cB.z * x1; a3[j] += cB.w * x1;
            a0[j] += cC.x * x2; a1[j] += cC.y * x2;
            a2[j] += cC.z * x2; a3[j] += cC.w * x2;
            a0[j] += cD.x * x3; a1[j] += cD.y * x3;
            a2[j] += cD.z * x3; a3[j] += cD.w * x3;
        }
    }
    for (; k < n; ++k) {
        unsigned p0 = ep[k];
        int s0 = p0 & 0xffffu, r0 = p0 >> 16;
        bf16x4 v0 = *(const bf16x4*)&xb[(size_t)s0 * D_IN + l * 4];
        float i0 = invf[d * R_REL + r0];
        float4 cA = *(const float4*)&coeffs[r0 * B_BAS];
        cA.x *= i0; cA.y *= i0; cA.z *= i0; cA.w *= i0;
        #pragma unroll
        for (int j = 0; j < 4; ++j) {
            float x0 = bf2f((unsigned short)v0[j]);
            a0[j] += cA.x * x0; a1[j] += cA.y * x0;
            a2[j] += cA.z * x0; a3[j] += cA.w * x0;
        }
    }
    // fragment-layout stores
    int rt = d >> 4, lrow = d & 15;
    int kc0 = l >> 3, lhi = (l >> 1) & 3, jj = (l & 1) * 4;
    size_t rowbase = (size_t)rt * (NKC * 512);   // shorts per rt = 20*64*8
    #pragma unroll
    for (int b = 0; b < 4; ++b) {
        const float* ab = (b == 0) ? a0 : (b == 1) ? a1 : (b == 2) ? a2 : a3;
        ushort4 o;
        o.x = f2bf(ab[0]); o.y = f2bf(ab[1]); o.z = f2bf(ab[2]); o.w = f2bf(ab[3]);
        size_t addr = rowbase + ((size_t)(b * 4 + kc0) * 64 + lhi * 16 + lrow) * 8 + jj;
        *(ushort4*)&yfrag[addr] = o;
    }
    ushort4 xv = *(const ushort4*)&xb[(size_t)d * D_IN + l * 4];
    size_t addr = rowbase + ((size_t)(16 + kc0) * 64 + lhi * 16 + lrow) * 8 + jj;
    *(ushort4*)&yfrag[addr] = xv;
}

// gemm2: out = relu(A @ Wstack + bias) with A,W pre-laid-out in fragment order.
// One wave per 16-row tile (50000 = 3125*16 exact). No LDS, no barriers,
// every load a full-wave-coalesced bf16x8.
__global__ __launch_bounds__(256) void gemm2_kernel(const unsigned short* __restrict__ yfrag,
                                                    const unsigned short* __restrict__ Wt2f,
                                                    const float* __restrict__ bias,
                                                    float* __restrict__ out) {
    const int w = threadIdx.x >> 6, l = threadIdx.x & 63;
    const int rt = blockIdx.x * 4 + w;
    if (rt >= NRT) return;
    const unsigned short* ya = yfrag + (size_t)rt * (NKC * 512);

    f32x4 acc[8] = {};
    #pragma unroll 4
    for (int kc = 0; kc < NKC; ++kc) {
        bf16x8 a = *(const bf16x8*)&ya[(kc * 64 + l) * 8];
        #pragma unroll
        for (int ct = 0; ct < 8; ++ct) {
            bf16x8 bfr = *(const bf16x8*)&Wt2f[((ct * NKC + kc) * 64 + l) * 8];
            acc[ct] = __builtin_amdgcn_mfma_f32_16x16x32_bf16(a, bfr, acc[ct], 0, 0, 0);
        }
    }

    // epilogue: C/D layout col=lane&15, row=(lane>>4)*4+i  [m89-verified]
    const int lr = l & 15, lg = l >> 4;
    #pragma unroll
    for (int ct = 0; ct < 8; ++ct) {
        float bv = bias[ct * 16 + lr];
        #pragma unroll
        for (int i2 = 0; i2 < 4; ++i2) {
            int row = rt * 16 + lg * 4 + i2;
            out[(size_t)row * O_OUT + ct * 16 + lr] = fmaxf(acc[ct][i2] + bv, 0.f);
        }
    }
}

extern "C" void kernel_launch(void* const* d_in, const int* in_sizes, int n_in,
                              void* d_out, int out_size, void* d_ws, size_t ws_size,
                              hipStream_t stream) {
    (void)in_sizes; (void)n_in; (void)out_size; (void)ws_size;
    const float* x       = (const float*)d_in[0];
    const float* basis_v = (const float*)d_in[1];
    const float* coeffs  = (const float*)d_in[2];
    const float* w_loop  = (const float*)d_in[3];
    const float* bias_p  = (const float*)d_in[4];
    const int*   src     = (const int*)d_in[5];
    const int*   dst     = (const int*)d_in[6];
    const int*   rel     = (const int*)d_in[7];
    float* out = (float*)d_out;

    char* ws = (char*)d_ws;
    unsigned short* Wt2f     = (unsigned short*)(ws);             //     163,840 B
    unsigned short* xb       = (unsigned short*)(ws + 163840);    //  12,800,000 B
    int*            deg      = (int*)(ws + 12963840);             //   1,600,000 B
    float*          invf     = (float*)(ws + 14563840);           //   1,600,000 B
    int*            cntd     = (int*)(ws + 16163840);             //     200,000 B
    int*            exoff    = (int*)(ws + 16363840);             //     200,000 B
    int*            bsum     = (int*)(ws + 16563840);             //       1,024 B
    int*            bbase    = (int*)(ws + 16564864);             //       1,024 B (99 ints)
    int*            cursor98 = (int*)(ws + 16565888);             //       1,024 B
    unsigned*       coarse   = (unsigned*)(ws + 16566912);        //   2,400,000 B
    unsigned*       epack    = (unsigned*)(ws + 18966912);        //   2,400,000 B
    unsigned short* yfrag    = (unsigned short*)(ws + 21366912);  //  64,000,000 B

    zero_kernel<<<(NSEG / 4 + 255) / 256, 256, 0, stream>>>((int4*)deg);
    prep_kernel<<<NB_CONV + NB_WT + NB_DEG, 256, 0, stream>>>(x, xb, basis_v, w_loop, Wt2f,
                                                              dst, rel, deg);
    scan1_kernel<<<NB1, 512, 0, stream>>>(deg, cntd, invf, exoff, bsum);
    scan2_kernel<<<1, 128, 0, stream>>>(bsum, bbase, cursor98);
    binA_kernel<<<NBA, 256, 0, stream>>>(src, dst, rel, cursor98, coarse);
    binB_kernel<<<NB1, 512, 0, stream>>>(coarse, bbase, exoff, epack);
    segagg_kernel<<<N_NODES / 8, 256, 0, stream>>>(xb, exoff, bbase, cntd, invf, epack,
                                                   coeffs, yfrag);
    gemm2_kernel<<<(NRT + 3) / 4, 256, 0, stream>>>(yfrag, Wt2f, bias_p, out);
}

// Round 13
// 137.746 us; speedup vs baseline: 1.1934x; 1.1319x over previous
//
#include <hip/hip_runtime.h>

#define N_NODES 50000
#define E_EDGES 600000
#define D_IN 128
#define O_OUT 128
#define R_REL 8
#define B_BAS 4
#define KTOT 640                  // 4 basis * 128 + self-loop 128
#define NSEG (N_NODES * R_REL)
#define NB1 98                    // ceil(50000/512): scan blocks == coarse buckets
#define NRT 3125                  // 50000 / 16 row tiles (exact)
#define NKC 20                    // 640 / 32 k-chunks

// prep kernel block ranges
#define NB_CONV 6250              // N*D/1024
#define NB_WT 320                 // 128*640/256
#define NB_DEG 2344               // ceil(E/256)

// binning
#define CHUNK_A 2048
#define NBA 293                   // ceil(600000/2048)

typedef __attribute__((ext_vector_type(8))) short bf16x8;
typedef __attribute__((ext_vector_type(4))) short bf16x4;
typedef __attribute__((ext_vector_type(4))) float f32x4;

static __device__ __forceinline__ unsigned short f2bf(float f) {
    unsigned int u = __float_as_uint(f);
    unsigned int r = (u + 0x7fffu + ((u >> 16) & 1u)) >> 16;
    return (unsigned short)r;
}
static __device__ __forceinline__ float bf2f(unsigned short b) {
    return __uint_as_float(((unsigned int)b) << 16);
}

// zero the deg table (NSEG ints = 100000 int4)
__global__ void zero_kernel(int4* __restrict__ deg4) {
    int i = blockIdx.x * 256 + threadIdx.x;
    if (i < NSEG / 4) deg4[i] = make_int4(0, 0, 0, 0);
}

// Fused: x->bf16 convert | Wt2f (fragment-layout weights) | per-(dst,rel) degree
// Wt2f[ct][kc][lane][j] = W[k][ct*16+(lane&15)], k = kc*32+(lane>>4)*8+j
__global__ __launch_bounds__(256) void prep_kernel(const float* __restrict__ x,
                                                   unsigned short* __restrict__ xb,
                                                   const float* __restrict__ basis_v,
                                                   const float* __restrict__ w_loop,
                                                   unsigned short* __restrict__ Wt2f,
                                                   const int* __restrict__ dst,
                                                   const int* __restrict__ rel,
                                                   int* __restrict__ deg) {
    int b = blockIdx.x;
    if (b < NB_CONV) {
        int i = (b * 256 + threadIdx.x) * 4;
        float4 v = *(const float4*)&x[i];
        ushort4 o;
        o.x = f2bf(v.x); o.y = f2bf(v.y); o.z = f2bf(v.z); o.w = f2bf(v.w);
        *(ushort4*)&xb[i] = o;
    } else if (b < NB_CONV + NB_WT) {
        int i = (b - NB_CONV) * 256 + threadIdx.x;  // over 8*20*64*8 = 81920
        int j = i & 7, l = (i >> 3) & 63, rest = i >> 9;
        int kc = rest % NKC, ct = rest / NKC;
        int col = ct * 16 + (l & 15);
        int k = kc * 32 + (l >> 4) * 8 + j;
        int r = k >> 7, d = k & 127;
        float v = (r < B_BAS) ? basis_v[((size_t)r * D_IN + d) * O_OUT + col]
                              : w_loop[(size_t)d * O_OUT + col];
        Wt2f[i] = f2bf(v);
    } else {
        int e = (b - NB_CONV - NB_WT) * 256 + threadIdx.x;
        if (e < E_EDGES) atomicAdd(&deg[dst[e] * R_REL + rel[e]], 1);
    }
}

// Per-dst total count + block-local exclusive scan; emits invf too
__global__ __launch_bounds__(512) void scan1_kernel(const int* __restrict__ deg,
                                                    int* __restrict__ cntd,
                                                    float* __restrict__ invf,
                                                    int* __restrict__ exoff,
                                                    int* __restrict__ bsum) {
    __shared__ int s[512];
    int t = threadIdx.x, i = blockIdx.x * 512 + t;
    int c = 0;
    if (i < N_NODES) {
        #pragma unroll
        for (int r = 0; r < R_REL; ++r) {
            int dg = deg[i * R_REL + r];
            c += dg;
            invf[i * R_REL + r] = 1.0f / (float)max(dg, 1);
        }
        cntd[i] = c;
    }
    s[t] = c;
    __syncthreads();
    #pragma unroll
    for (int off = 1; off < 512; off <<= 1) {
        int add = (t >= off) ? s[t - off] : 0;
        __syncthreads();
        s[t] += add;
        __syncthreads();
    }
    if (i < N_NODES) exoff[i] = s[t] - c;
    if (t == 511) bsum[blockIdx.x] = s[511];
}

// Scan 98 block sums -> bbase[0..98]; init cursor98 copy
__global__ __launch_bounds__(128) void scan2_kernel(const int* __restrict__ bsum,
                                                    int* __restrict__ bbase,
                                                    int* __restrict__ cursor98) {
    __shared__ int s[128];
    int t = threadIdx.x;
    int c = (t < NB1) ? bsum[t] : 0;
    s[t] = c;
    __syncthreads();
    #pragma unroll
    for (int off = 1; off < 128; off <<= 1) {
        int add = (t >= off) ? s[t - off] : 0;
        __syncthreads();
        s[t] += add;
        __syncthreads();
    }
    if (t < NB1) {
        int v = s[t] - c;
        bbase[t] = v;
        cursor98[t] = v;
    }
    if (t == NB1 - 1) bbase[NB1] = s[t];
}

// Pass A: bin edges into 98 coarse buckets (512 dsts each), block-contiguous runs.
// coarse payload: src(16) | rel(3)<<16 | dlow(9)<<19
__global__ __launch_bounds__(256) void binA_kernel(const int* __restrict__ src,
                                                   const int* __restrict__ dst,
                                                   const int* __restrict__ rel,
                                                   int* __restrict__ cursor98,
                                                   unsigned* __restrict__ coarse) {
    __shared__ int hist[NB1];
    __shared__ int base[NB1];
    int t = threadIdx.x;
    if (t < NB1) hist[t] = 0;
    __syncthreads();
    int e0 = blockIdx.x * CHUNK_A;
    for (int i = t; i < CHUNK_A; i += 256) {
        int e = e0 + i;
        if (e < E_EDGES) atomicAdd(&hist[dst[e] >> 9], 1);
    }
    __syncthreads();
    if (t < NB1) {
        int h = hist[t];
        base[t] = h ? atomicAdd(&cursor98[t], h) : 0;
        hist[t] = 0;
    }
    __syncthreads();
    for (int i = t; i < CHUNK_A; i += 256) {
        int e = e0 + i;
        if (e < E_EDGES) {
            int d = dst[e], b = d >> 9;
            int pos = base[b] + atomicAdd(&hist[b], 1);
            coarse[pos] = (unsigned)src[e] | ((unsigned)rel[e] << 16)
                        | ((unsigned)(d & 511) << 19);
        }
    }
}

// Pass B: one block per coarse bucket; exact per-dst slots via LDS counters.
__global__ __launch_bounds__(512) void binB_kernel(const unsigned* __restrict__ coarse,
                                                   const int* __restrict__ bbase,
                                                   const int* __restrict__ exoff,
                                                   unsigned* __restrict__ epack) {
    __shared__ int lcnt[512];
    int b = blockIdx.x, t = threadIdx.x;
    int d0 = b << 9;
    lcnt[t] = (d0 + t < N_NODES) ? exoff[d0 + t] : 0;
    __syncthreads();
    int s0 = bbase[b], s1 = bbase[b + 1];
    for (int i = s0 + t; i < s1; i += 512) {
        unsigned p = coarse[i];
        int dlow = (p >> 19) & 511;
        int pos = s0 + atomicAdd(&lcnt[dlow], 1);
        epack[pos] = p & 0x7ffffu;  // src | rel<<16
    }
}

// segagg: 32 lanes per dst node; 4-deep pipelined edge walk.
// Writes yfrag in MFMA fragment order (see round-12 comments).
__global__ __launch_bounds__(256) void segagg_kernel(const unsigned short* __restrict__ xb,
                                                     const int* __restrict__ exoff,
                                                     const int* __restrict__ bbase,
                                                     const int* __restrict__ cntd,
                                                     const float* __restrict__ invf,
                                                     const unsigned* __restrict__ epack,
                                                     const float* __restrict__ coeffs,
                                                     unsigned short* __restrict__ yfrag) {
    int d = blockIdx.x * 8 + (threadIdx.x >> 5);  // grid exact: 50000/8
    int l = threadIdx.x & 31;
    int beg = exoff[d] + bbase[d >> 9];
    int n = cntd[d];
    const unsigned* ep = epack + beg;
    float a0[4] = {}, a1[4] = {}, a2[4] = {}, a3[4] = {};
    int k = 0;
    for (; k + 4 <= n; k += 4) {
        unsigned p0 = ep[k], p1 = ep[k + 1], p2 = ep[k + 2], p3 = ep[k + 3];
        int s0 = p0 & 0xffffu, r0 = p0 >> 16;
        int s1 = p1 & 0xffffu, r1 = p1 >> 16;
        int s2 = p2 & 0xffffu, r2 = p2 >> 16;
        int s3 = p3 & 0xffffu, r3 = p3 >> 16;
        bf16x4 v0 = *(const bf16x4*)&xb[(size_t)s0 * D_IN + l * 4];
        bf16x4 v1 = *(const bf16x4*)&xb[(size_t)s1 * D_IN + l * 4];
        bf16x4 v2 = *(const bf16x4*)&xb[(size_t)s2 * D_IN + l * 4];
        bf16x4 v3 = *(const bf16x4*)&xb[(size_t)s3 * D_IN + l * 4];
        float i0 = invf[d * R_REL + r0];
        float i1 = invf[d * R_REL + r1];
        float i2 = invf[d * R_REL + r2];
        float i3 = invf[d * R_REL + r3];
        float4 cA = *(const float4*)&coeffs[r0 * B_BAS];
        float4 cB = *(const float4*)&coeffs[r1 * B_BAS];
        float4 cC = *(const float4*)&coeffs[r2 * B_BAS];
        float4 cD = *(const float4*)&coeffs[r3 * B_BAS];
        cA.x *= i0; cA.y *= i0; cA.z *= i0; cA.w *= i0;
        cB.x *= i1; cB.y *= i1; cB.z *= i1; cB.w *= i1;
        cC.x *= i2; cC.y *= i2; cC.z *= i2; cC.w *= i2;
        cD.x *= i3; cD.y *= i3; cD.z *= i3; cD.w *= i3;
        #pragma unroll
        for (int j = 0; j < 4; ++j) {
            float x0 = bf2f((unsigned short)v0[j]);
            float x1 = bf2f((unsigned short)v1[j]);
            float x2 = bf2f((unsigned short)v2[j]);
            float x3 = bf2f((unsigned short)v3[j]);
            a0[j] += cA.x * x0; a1[j] += cA.y * x0;
            a2[j] += cA.z * x0; a3[j] += cA.w * x0;
            a0[j] += cB.x * x1; a1[j] += cB.y * x1;
            a2[j] += cB.z * x1; a3[j] += cB.w * x1;
            a0[j] += cC.x * x2; a1[j] += cC.y * x2;
            a2[j] += cC.z * x2; a3[j] += cC.w * x2;
            a0[j] += cD.x * x3; a1[j] += cD.y * x3;
            a2[j] += cD.z * x3; a3[j] += cD.w * x3;
        }
    }
    for (; k < n; ++k) {
        unsigned p0 = ep[k];
        int s0 = p0 & 0xffffu, r0 = p0 >> 16;
        bf16x4 v0 = *(const bf16x4*)&xb[(size_t)s0 * D_IN + l * 4];
        float i0 = invf[d * R_REL + r0];
        float4 cA = *(const float4*)&coeffs[r0 * B_BAS];
        cA.x *= i0; cA.y *= i0; cA.z *= i0; cA.w *= i0;
        #pragma unroll
        for (int j = 0; j < 4; ++j) {
            float x0 = bf2f((unsigned short)v0[j]);
            a0[j] += cA.x * x0; a1[j] += cA.y * x0;
            a2[j] += cA.z * x0; a3[j] += cA.w * x0;
        }
    }
    // fragment-layout stores
    int rt = d >> 4, lrow = d & 15;
    int kc0 = l >> 3, lhi = (l >> 1) & 3, jj = (l & 1) * 4;
    size_t rowbase = (size_t)rt * (NKC * 512);   // shorts per rt = 20*64*8
    #pragma unroll
    for (int b = 0; b < 4; ++b) {
        const float* ab = (b == 0) ? a0 : (b == 1) ? a1 : (b == 2) ? a2 : a3;
        ushort4 o;
        o.x = f2bf(ab[0]); o.y = f2bf(ab[1]); o.z = f2bf(ab[2]); o.w = f2bf(ab[3]);
        size_t addr = rowbase + ((size_t)(b * 4 + kc0) * 64 + lhi * 16 + lrow) * 8 + jj;
        *(ushort4*)&yfrag[addr] = o;
    }
    ushort4 xv = *(const ushort4*)&xb[(size_t)d * D_IN + l * 4];
    size_t addr = rowbase + ((size_t)(16 + kc0) * 64 + lhi * 16 + lrow) * 8 + jj;
    *(ushort4*)&yfrag[addr] = xv;
}

// gemm2: out = relu(A @ Wstack + bias), fragment-layout operands.
// Each wave: 16 rows x 64 cols (4 ct) -> 6250 waves. Explicit even/odd
// 2-slot software pipeline with named registers (no runtime reg indexing).
__global__ __launch_bounds__(256) void gemm2_kernel(const unsigned short* __restrict__ yfrag,
                                                    const unsigned short* __restrict__ Wt2f,
                                                    const float* __restrict__ bias,
                                                    float* __restrict__ out) {
    const int w = threadIdx.x >> 6, l = threadIdx.x & 63;
    const int wid = blockIdx.x * 4 + w;
    if (wid >= NRT * 2) return;
    const int rt = wid >> 1;
    const int ch = wid & 1;                    // col half: ct base 0 or 4
    const unsigned short* ya = yfrag + (size_t)rt * (NKC * 512) + l * 8;
    const unsigned short* wb = Wt2f + (size_t)(ch * 4) * (NKC * 512) + l * 8;
    const int KSTEP = 512;                     // shorts per kc slab

    f32x4 acc0 = {}, acc1 = {}, acc2 = {}, acc3 = {};

#define LOADA(kc) (*(const bf16x8*)&ya[(kc) * KSTEP])
#define LOADB(ct, kc) (*(const bf16x8*)&wb[((ct) * NKC + (kc)) * KSTEP])

    // preload kc=0 (even slot) and kc=1 (odd slot)
    bf16x8 aE = LOADA(0);
    bf16x8 bE0 = LOADB(0, 0), bE1 = LOADB(1, 0), bE2 = LOADB(2, 0), bE3 = LOADB(3, 0);
    bf16x8 aO = LOADA(1);
    bf16x8 bO0 = LOADB(0, 1), bO1 = LOADB(1, 1), bO2 = LOADB(2, 1), bO3 = LOADB(3, 1);

    #pragma unroll
    for (int kc = 0; kc < NKC; kc += 2) {
        // consume even slot (kc), then refill it for kc+2
        acc0 = __builtin_amdgcn_mfma_f32_16x16x32_bf16(aE, bE0, acc0, 0, 0, 0);
        acc1 = __builtin_amdgcn_mfma_f32_16x16x32_bf16(aE, bE1, acc1, 0, 0, 0);
        acc2 = __builtin_amdgcn_mfma_f32_16x16x32_bf16(aE, bE2, acc2, 0, 0, 0);
        acc3 = __builtin_amdgcn_mfma_f32_16x16x32_bf16(aE, bE3, acc3, 0, 0, 0);
        if (kc + 2 < NKC) {
            aE = LOADA(kc + 2);
            bE0 = LOADB(0, kc + 2); bE1 = LOADB(1, kc + 2);
            bE2 = LOADB(2, kc + 2); bE3 = LOADB(3, kc + 2);
        }
        // consume odd slot (kc+1), then refill it for kc+3
        acc0 = __builtin_amdgcn_mfma_f32_16x16x32_bf16(aO, bO0, acc0, 0, 0, 0);
        acc1 = __builtin_amdgcn_mfma_f32_16x16x32_bf16(aO, bO1, acc1, 0, 0, 0);
        acc2 = __builtin_amdgcn_mfma_f32_16x16x32_bf16(aO, bO2, acc2, 0, 0, 0);
        acc3 = __builtin_amdgcn_mfma_f32_16x16x32_bf16(aO, bO3, acc3, 0, 0, 0);
        if (kc + 3 < NKC) {
            aO = LOADA(kc + 3);
            bO0 = LOADB(0, kc + 3); bO1 = LOADB(1, kc + 3);
            bO2 = LOADB(2, kc + 3); bO3 = LOADB(3, kc + 3);
        }
    }
#undef LOADA
#undef LOADB

    // epilogue: C/D layout col=lane&15, row=(lane>>4)*4+i  [m89-verified]
    const int lr = l & 15, lg = l >> 4;
    #pragma unroll
    for (int ct = 0; ct < 4; ++ct) {
        const f32x4& a = (ct == 0) ? acc0 : (ct == 1) ? acc1 : (ct == 2) ? acc2 : acc3;
        int col = (ch * 4 + ct) * 16 + lr;
        float bv = bias[col];
        #pragma unroll
        for (int i2 = 0; i2 < 4; ++i2) {
            int row = rt * 16 + lg * 4 + i2;
            out[(size_t)row * O_OUT + col] = fmaxf(a[i2] + bv, 0.f);
        }
    }
}

extern "C" void kernel_launch(void* const* d_in, const int* in_sizes, int n_in,
                              void* d_out, int out_size, void* d_ws, size_t ws_size,
                              hipStream_t stream) {
    (void)in_sizes; (void)n_in; (void)out_size; (void)ws_size;
    const float* x       = (const float*)d_in[0];
    const float* basis_v = (const float*)d_in[1];
    const float* coeffs  = (const float*)d_in[2];
    const float* w_loop  = (const float*)d_in[3];
    const float* bias_p  = (const float*)d_in[4];
    const int*   src     = (const int*)d_in[5];
    const int*   dst     = (const int*)d_in[6];
    const int*   rel     = (const int*)d_in[7];
    float* out = (float*)d_out;

    char* ws = (char*)d_ws;
    unsigned short* Wt2f     = (unsigned short*)(ws);             //     163,840 B
    unsigned short* xb       = (unsigned short*)(ws + 163840);    //  12,800,000 B
    int*            deg      = (int*)(ws + 12963840);             //   1,600,000 B
    float*          invf     = (float*)(ws + 14563840);           //   1,600,000 B
    int*            cntd     = (int*)(ws + 16163840);             //     200,000 B
    int*            exoff    = (int*)(ws + 16363840);             //     200,000 B
    int*            bsum     = (int*)(ws + 16563840);             //       1,024 B
    int*            bbase    = (int*)(ws + 16564864);             //       1,024 B (99 ints)
    int*            cursor98 = (int*)(ws + 16565888);             //       1,024 B
    unsigned*       coarse   = (unsigned*)(ws + 16566912);        //   2,400,000 B
    unsigned*       epack    = (unsigned*)(ws + 18966912);        //   2,400,000 B
    unsigned short* yfrag    = (unsigned short*)(ws + 21366912);  //  64,000,000 B

    zero_kernel<<<(NSEG / 4 + 255) / 256, 256, 0, stream>>>((int4*)deg);
    prep_kernel<<<NB_CONV + NB_WT + NB_DEG, 256, 0, stream>>>(x, xb, basis_v, w_loop, Wt2f,
                                                              dst, rel, deg);
    scan1_kernel<<<NB1, 512, 0, stream>>>(deg, cntd, invf, exoff, bsum);
    scan2_kernel<<<1, 128, 0, stream>>>(bsum, bbase, cursor98);
    binA_kernel<<<NBA, 256, 0, stream>>>(src, dst, rel, cursor98, coarse);
    binB_kernel<<<NB1, 512, 0, stream>>>(coarse, bbase, exoff, epack);
    segagg_kernel<<<N_NODES / 8, 256, 0, stream>>>(xb, exoff, bbase, cntd, invf, epack,
                                                   coeffs, yfrag);
    gemm2_kernel<<<(NRT * 2 + 3) / 4, 256, 0, stream>>>(yfrag, Wt2f, bias_p, out);
}

// Round 14
// 120.068 us; speedup vs baseline: 1.3692x; 1.1472x over previous
//
#include <hip/hip_runtime.h>

#define N_NODES 50000
#define E_EDGES 600000
#define D_IN 128
#define O_OUT 128
#define R_REL 8
#define B_BAS 4
#define NB1 98                    // coarse buckets (512 dsts each)
#define NRT 3125                  // 50000 / 16 row tiles (exact)
#define NKC 20                    // 640 / 32 k-chunks
#define BKCAP 8192                // fixed per-bucket capacity (mean 6122, +26 sigma)

// prep kernel block ranges
#define NB_CONV 6250              // N*D/1024
#define NB_WT 320                 // 128*640/256

// binning
#define CHUNK_A 2048
#define NBA 293                   // ceil(600000/2048)

typedef __attribute__((ext_vector_type(8))) short bf16x8;
typedef __attribute__((ext_vector_type(4))) short bf16x4;
typedef __attribute__((ext_vector_type(4))) float f32x4;

static __device__ __forceinline__ unsigned short f2bf(float f) {
    unsigned int u = __float_as_uint(f);
    unsigned int r = (u + 0x7fffu + ((u >> 16) & 1u)) >> 16;
    return (unsigned short)r;
}
static __device__ __forceinline__ float bf2f(unsigned short b) {
    return __uint_as_float(((unsigned int)b) << 16);
}

// Fused: x->bf16 convert | Wt2f (fragment-layout weights). Block 0 also zeroes cursor98.
__global__ __launch_bounds__(256) void prep_kernel(const float* __restrict__ x,
                                                   unsigned short* __restrict__ xb,
                                                   const float* __restrict__ basis_v,
                                                   const float* __restrict__ w_loop,
                                                   unsigned short* __restrict__ Wt2f,
                                                   int* __restrict__ cursor98) {
    int b = blockIdx.x;
    if (b == 0 && threadIdx.x < NB1) cursor98[threadIdx.x] = 0;
    if (b < NB_CONV) {
        int i = (b * 256 + threadIdx.x) * 4;
        float4 v = *(const float4*)&x[i];
        ushort4 o;
        o.x = f2bf(v.x); o.y = f2bf(v.y); o.z = f2bf(v.z); o.w = f2bf(v.w);
        *(ushort4*)&xb[i] = o;
    } else {
        int i = (b - NB_CONV) * 256 + threadIdx.x;  // over 8*20*64*8 = 81920
        int j = i & 7, l = (i >> 3) & 63, rest = i >> 9;
        int kc = rest % NKC, ct = rest / NKC;
        int col = ct * 16 + (l & 15);
        int k = kc * 32 + (l >> 4) * 8 + j;
        int r = k >> 7, d = k & 127;
        float v = (r < B_BAS) ? basis_v[((size_t)r * D_IN + d) * O_OUT + col]
                              : w_loop[(size_t)d * O_OUT + col];
        Wt2f[i] = f2bf(v);
    }
}

// Pass A: bin edges into 98 fixed-capacity coarse buckets, block-contiguous runs.
// coarse payload: src(16) | rel(3)<<16 | dlow(9)<<19
__global__ __launch_bounds__(256) void binA_kernel(const int* __restrict__ src,
                                                   const int* __restrict__ dst,
                                                   const int* __restrict__ rel,
                                                   int* __restrict__ cursor98,
                                                   unsigned* __restrict__ coarse) {
    __shared__ int hist[NB1];
    __shared__ int base[NB1];
    int t = threadIdx.x;
    if (t < NB1) hist[t] = 0;
    __syncthreads();
    int e0 = blockIdx.x * CHUNK_A;
    for (int i = t; i < CHUNK_A; i += 256) {
        int e = e0 + i;
        if (e < E_EDGES) atomicAdd(&hist[dst[e] >> 9], 1);
    }
    __syncthreads();
    if (t < NB1) {
        int h = hist[t];
        base[t] = h ? atomicAdd(&cursor98[t], h) : 0;
        hist[t] = 0;
    }
    __syncthreads();
    for (int i = t; i < CHUNK_A; i += 256) {
        int e = e0 + i;
        if (e < E_EDGES) {
            int d = dst[e], b = d >> 9;
            int pos = base[b] + atomicAdd(&hist[b], 1);
            coarse[(size_t)b * BKCAP + pos] = (unsigned)src[e] | ((unsigned)rel[e] << 16)
                                            | ((unsigned)(d & 511) << 19);
        }
    }
}

// Pass B: one block per bucket. LDS (dst,rel) histogram -> invf + per-dst scan
// (begd/cntd) -> exact slot placement. Replaces deg/zero/scan1/scan2.
__global__ __launch_bounds__(512) void binB_kernel(const unsigned* __restrict__ coarse,
                                                   const int* __restrict__ cursor98,
                                                   unsigned* __restrict__ epack,
                                                   int* __restrict__ begd,
                                                   int* __restrict__ cntd,
                                                   float* __restrict__ invf) {
    __shared__ int hist[512 * 8];   // 16 KB: [dlow][rel]
    __shared__ int s[512];
    __shared__ int lcnt[512];
    int b = blockIdx.x, t = threadIdx.x;
    int d0 = b << 9, d = d0 + t;
    #pragma unroll
    for (int r = 0; r < 8; ++r) hist[t * 8 + r] = 0;
    __syncthreads();
    int cnt = cursor98[b];
    const unsigned* cb = coarse + (size_t)b * BKCAP;
    for (int i = t; i < cnt; i += 512) {
        unsigned p = cb[i];
        atomicAdd(&hist[((p >> 19) & 511) * 8 + ((p >> 16) & 7)], 1);
    }
    __syncthreads();
    int c = 0;
    if (d < N_NODES) {
        #pragma unroll
        for (int r = 0; r < 8; ++r) {
            int h = hist[t * 8 + r];
            c += h;
            invf[d * 8 + r] = 1.0f / (float)max(h, 1);
        }
    }
    s[t] = c;
    __syncthreads();
    #pragma unroll
    for (int off = 1; off < 512; off <<= 1) {
        int add = (t >= off) ? s[t - off] : 0;
        __syncthreads();
        s[t] += add;
        __syncthreads();
    }
    int ex = s[t] - c;
    if (d < N_NODES) {
        begd[d] = b * BKCAP + ex;
        cntd[d] = c;
    }
    lcnt[t] = ex;
    __syncthreads();
    for (int i = t; i < cnt; i += 512) {
        unsigned p = cb[i];
        int dlow = (p >> 19) & 511;
        int pos = atomicAdd(&lcnt[dlow], 1);
        epack[(size_t)b * BKCAP + pos] = p & 0x7ffffu;  // src | rel<<16
    }
}

// segagg: 32 lanes per dst node; 8/4/1 cascaded pipelined edge walk.
// Writes yfrag in MFMA fragment order:
//   lane l holds k = b*128 + l*4 + m -> kc=b*4+(l>>3), lhi=(l>>1)&3, j=(l&1)*4+m
#define EDGE_VARS(p, vv, cc)                                             \
    {                                                                    \
        int s_ = (p) & 0xffffu, r_ = (p) >> 16;                          \
        vv = *(const bf16x4*)&xb[(size_t)s_ * D_IN + l * 4];             \
        float i_ = invf[d * R_REL + r_];                                 \
        cc = *(const float4*)&coeffs[r_ * B_BAS];                        \
        cc.x *= i_; cc.y *= i_; cc.z *= i_; cc.w *= i_;                  \
    }
#define EDGE_ACC(vv, cc)                                                 \
    _Pragma("unroll")                                                    \
    for (int j = 0; j < 4; ++j) {                                        \
        float x_ = bf2f((unsigned short)vv[j]);                          \
        a0[j] += cc.x * x_; a1[j] += cc.y * x_;                          \
        a2[j] += cc.z * x_; a3[j] += cc.w * x_;                          \
    }

__global__ __launch_bounds__(256) void segagg_kernel(const unsigned short* __restrict__ xb,
                                                     const int* __restrict__ begd,
                                                     const int* __restrict__ cntd,
                                                     const float* __restrict__ invf,
                                                     const unsigned* __restrict__ epack,
                                                     const float* __restrict__ coeffs,
                                                     unsigned short* __restrict__ yfrag) {
    int d = blockIdx.x * 8 + (threadIdx.x >> 5);  // grid exact: 50000/8
    int l = threadIdx.x & 31;
    int beg = begd[d];
    int n = cntd[d];
    const unsigned* ep = epack + beg;
    float a0[4] = {}, a1[4] = {}, a2[4] = {}, a3[4] = {};
    int k = 0;
    for (; k + 8 <= n; k += 8) {
        unsigned p0 = ep[k], p1 = ep[k + 1], p2 = ep[k + 2], p3 = ep[k + 3];
        unsigned p4 = ep[k + 4], p5 = ep[k + 5], p6 = ep[k + 6], p7 = ep[k + 7];
        bf16x4 v0, v1, v2, v3, v4, v5, v6, v7;
        float4 c0, c1, c2, c3, c4, c5, c6, c7;
        EDGE_VARS(p0, v0, c0) EDGE_VARS(p1, v1, c1)
        EDGE_VARS(p2, v2, c2) EDGE_VARS(p3, v3, c3)
        EDGE_VARS(p4, v4, c4) EDGE_VARS(p5, v5, c5)
        EDGE_VARS(p6, v6, c6) EDGE_VARS(p7, v7, c7)
        EDGE_ACC(v0, c0) EDGE_ACC(v1, c1) EDGE_ACC(v2, c2) EDGE_ACC(v3, c3)
        EDGE_ACC(v4, c4) EDGE_ACC(v5, c5) EDGE_ACC(v6, c6) EDGE_ACC(v7, c7)
    }
    if (k + 4 <= n) {
        unsigned p0 = ep[k], p1 = ep[k + 1], p2 = ep[k + 2], p3 = ep[k + 3];
        bf16x4 v0, v1, v2, v3;
        float4 c0, c1, c2, c3;
        EDGE_VARS(p0, v0, c0) EDGE_VARS(p1, v1, c1)
        EDGE_VARS(p2, v2, c2) EDGE_VARS(p3, v3, c3)
        EDGE_ACC(v0, c0) EDGE_ACC(v1, c1) EDGE_ACC(v2, c2) EDGE_ACC(v3, c3)
        k += 4;
    }
    for (; k < n; ++k) {
        unsigned p0 = ep[k];
        bf16x4 v0;
        float4 c0;
        EDGE_VARS(p0, v0, c0)
        EDGE_ACC(v0, c0)
    }
    // fragment-layout stores
    int rt = d >> 4, lrow = d & 15;
    int kc0 = l >> 3, lhi = (l >> 1) & 3, jj = (l & 1) * 4;
    size_t rowbase = (size_t)rt * (NKC * 512);   // shorts per rt = 20*64*8
    #pragma unroll
    for (int b = 0; b < 4; ++b) {
        const float* ab = (b == 0) ? a0 : (b == 1) ? a1 : (b == 2) ? a2 : a3;
        ushort4 o;
        o.x = f2bf(ab[0]); o.y = f2bf(ab[1]); o.z = f2bf(ab[2]); o.w = f2bf(ab[3]);
        size_t addr = rowbase + ((size_t)(b * 4 + kc0) * 64 + lhi * 16 + lrow) * 8 + jj;
        *(ushort4*)&yfrag[addr] = o;
    }
    ushort4 xv = *(const ushort4*)&xb[(size_t)d * D_IN + l * 4];
    size_t addr = rowbase + ((size_t)(16 + kc0) * 64 + lhi * 16 + lrow) * 8 + jj;
    *(ushort4*)&yfrag[addr] = xv;
}

// gemm2: out = relu(A @ Wstack + bias), fragment-layout operands.
// Each wave: 16 rows x 64 cols (4 ct) -> 6250 waves. Explicit even/odd
// 2-slot software pipeline with named registers.
__global__ __launch_bounds__(256) void gemm2_kernel(const unsigned short* __restrict__ yfrag,
                                                    const unsigned short* __restrict__ Wt2f,
                                                    const float* __restrict__ bias,
                                                    float* __restrict__ out) {
    const int w = threadIdx.x >> 6, l = threadIdx.x & 63;
    const int wid = blockIdx.x * 4 + w;
    if (wid >= NRT * 2) return;
    const int rt = wid >> 1;
    const int ch = wid & 1;                    // col half: ct base 0 or 4
    const unsigned short* ya = yfrag + (size_t)rt * (NKC * 512) + l * 8;
    const unsigned short* wb = Wt2f + (size_t)(ch * 4) * (NKC * 512) + l * 8;
    const int KSTEP = 512;

    f32x4 acc0 = {}, acc1 = {}, acc2 = {}, acc3 = {};

#define LOADA(kc) (*(const bf16x8*)&ya[(kc) * KSTEP])
#define LOADB(ct, kc) (*(const bf16x8*)&wb[((ct) * NKC + (kc)) * KSTEP])

    bf16x8 aE = LOADA(0);
    bf16x8 bE0 = LOADB(0, 0), bE1 = LOADB(1, 0), bE2 = LOADB(2, 0), bE3 = LOADB(3, 0);
    bf16x8 aO = LOADA(1);
    bf16x8 bO0 = LOADB(0, 1), bO1 = LOADB(1, 1), bO2 = LOADB(2, 1), bO3 = LOADB(3, 1);

    #pragma unroll
    for (int kc = 0; kc < NKC; kc += 2) {
        acc0 = __builtin_amdgcn_mfma_f32_16x16x32_bf16(aE, bE0, acc0, 0, 0, 0);
        acc1 = __builtin_amdgcn_mfma_f32_16x16x32_bf16(aE, bE1, acc1, 0, 0, 0);
        acc2 = __builtin_amdgcn_mfma_f32_16x16x32_bf16(aE, bE2, acc2, 0, 0, 0);
        acc3 = __builtin_amdgcn_mfma_f32_16x16x32_bf16(aE, bE3, acc3, 0, 0, 0);
        if (kc + 2 < NKC) {
            aE = LOADA(kc + 2);
            bE0 = LOADB(0, kc + 2); bE1 = LOADB(1, kc + 2);
            bE2 = LOADB(2, kc + 2); bE3 = LOADB(3, kc + 2);
        }
        acc0 = __builtin_amdgcn_mfma_f32_16x16x32_bf16(aO, bO0, acc0, 0, 0, 0);
        acc1 = __builtin_amdgcn_mfma_f32_16x16x32_bf16(aO, bO1, acc1, 0, 0, 0);
        acc2 = __builtin_amdgcn_mfma_f32_16x16x32_bf16(aO, bO2, acc2, 0, 0, 0);
        acc3 = __builtin_amdgcn_mfma_f32_16x16x32_bf16(aO, bO3, acc3, 0, 0, 0);
        if (kc + 3 < NKC) {
            aO = LOADA(kc + 3);
            bO0 = LOADB(0, kc + 3); bO1 = LOADB(1, kc + 3);
            bO2 = LOADB(2, kc + 3); bO3 = LOADB(3, kc + 3);
        }
    }
#undef LOADA
#undef LOADB

    // epilogue: C/D layout col=lane&15, row=(lane>>4)*4+i  [m89-verified]
    const int lr = l & 15, lg = l >> 4;
    #pragma unroll
    for (int ct = 0; ct < 4; ++ct) {
        const f32x4& a = (ct == 0) ? acc0 : (ct == 1) ? acc1 : (ct == 2) ? acc2 : acc3;
        int col = (ch * 4 + ct) * 16 + lr;
        float bv = bias[col];
        #pragma unroll
        for (int i2 = 0; i2 < 4; ++i2) {
            int row = rt * 16 + lg * 4 + i2;
            out[(size_t)row * O_OUT + col] = fmaxf(a[i2] + bv, 0.f);
        }
    }
}

extern "C" void kernel_launch(void* const* d_in, const int* in_sizes, int n_in,
                              void* d_out, int out_size, void* d_ws, size_t ws_size,
                              hipStream_t stream) {
    (void)in_sizes; (void)n_in; (void)out_size; (void)ws_size;
    const float* x       = (const float*)d_in[0];
    const float* basis_v = (const float*)d_in[1];
    const float* coeffs  = (const float*)d_in[2];
    const float* w_loop  = (const float*)d_in[3];
    const float* bias_p  = (const float*)d_in[4];
    const int*   src     = (const int*)d_in[5];
    const int*   dst     = (const int*)d_in[6];
    const int*   rel     = (const int*)d_in[7];
    float* out = (float*)d_out;

    char* ws = (char*)d_ws;
    unsigned short* Wt2f     = (unsigned short*)(ws);             //     163,840 B
    unsigned short* xb       = (unsigned short*)(ws + 163840);    //  12,800,000 B
    float*          invf     = (float*)(ws + 12963840);           //   1,600,000 B
    int*            begd     = (int*)(ws + 14563840);             //     200,000 B
    int*            cntd     = (int*)(ws + 14763840);             //     200,000 B
    int*            cursor98 = (int*)(ws + 14963840);             //       1,024 B
    unsigned*       coarse   = (unsigned*)(ws + 14964864);        //   3,211,264 B
    unsigned*       epack    = (unsigned*)(ws + 18176128);        //   3,211,264 B
    unsigned short* yfrag    = (unsigned short*)(ws + 21387392);  //  64,000,000 B

    prep_kernel<<<NB_CONV + NB_WT, 256, 0, stream>>>(x, xb, basis_v, w_loop, Wt2f, cursor98);
    binA_kernel<<<NBA, 256, 0, stream>>>(src, dst, rel, cursor98, coarse);
    binB_kernel<<<NB1, 512, 0, stream>>>(coarse, cursor98, epack, begd, cntd, invf);
    segagg_kernel<<<N_NODES / 8, 256, 0, stream>>>(xb, begd, cntd, invf, epack, coeffs, yfrag);
    gemm2_kernel<<<(NRT * 2 + 3) / 4, 256, 0, stream>>>(yfrag, Wt2f, bias_p, out);
}

// Round 15
// 101.090 us; speedup vs baseline: 1.6262x; 1.1877x over previous
//
#include <hip/hip_runtime.h>

#define N_NODES 50000
#define E_EDGES 600000
#define D_IN 128
#define O_OUT 128
#define R_REL 8
#define B_BAS 4
#define NB1 98                    // coarse buckets (512 dsts each)
#define NRT 3125                  // 50000 / 16 row tiles (exact)
#define NKC 20                    // 640 / 32 k-chunks
#define BKCAP 8192                // fixed per-bucket capacity (mean 6122, +26 sigma)
#define NRG 1563                  // ceil(50000/32) 32-row groups for gemm2

// prep kernel block ranges
#define NB_CONV 6250              // N*D/1024
#define NB_WT 320                 // 128*640/256

// binning
#define CHUNK_A 2048
#define NBA 293                   // ceil(600000/2048)

typedef __attribute__((ext_vector_type(8))) short bf16x8;
typedef __attribute__((ext_vector_type(4))) short bf16x4;
typedef __attribute__((ext_vector_type(4))) float f32x4;

static __device__ __forceinline__ unsigned short f2bf(float f) {
    unsigned int u = __float_as_uint(f);
    unsigned int r = (u + 0x7fffu + ((u >> 16) & 1u)) >> 16;
    return (unsigned short)r;
}
static __device__ __forceinline__ float bf2f(unsigned short b) {
    return __uint_as_float(((unsigned int)b) << 16);
}

// Fused: x->bf16 convert | Wt2f (fragment-layout weights). Block 0 also zeroes cursor98.
__global__ __launch_bounds__(256) void prep_kernel(const float* __restrict__ x,
                                                   unsigned short* __restrict__ xb,
                                                   const float* __restrict__ basis_v,
                                                   const float* __restrict__ w_loop,
                                                   unsigned short* __restrict__ Wt2f,
                                                   int* __restrict__ cursor98) {
    int b = blockIdx.x;
    if (b == 0 && threadIdx.x < NB1) cursor98[threadIdx.x] = 0;
    if (b < NB_CONV) {
        int i = (b * 256 + threadIdx.x) * 4;
        float4 v = *(const float4*)&x[i];
        ushort4 o;
        o.x = f2bf(v.x); o.y = f2bf(v.y); o.z = f2bf(v.z); o.w = f2bf(v.w);
        *(ushort4*)&xb[i] = o;
    } else {
        int i = (b - NB_CONV) * 256 + threadIdx.x;  // over 8*20*64*8 = 81920
        int j = i & 7, l = (i >> 3) & 63, rest = i >> 9;
        int kc = rest % NKC, ct = rest / NKC;
        int col = ct * 16 + (l & 15);
        int k = kc * 32 + (l >> 4) * 8 + j;
        int r = k >> 7, d = k & 127;
        float v = (r < B_BAS) ? basis_v[((size_t)r * D_IN + d) * O_OUT + col]
                              : w_loop[(size_t)d * O_OUT + col];
        Wt2f[i] = f2bf(v);
    }
}

// Pass A: bin edges into 98 fixed-capacity coarse buckets, block-contiguous runs.
// coarse payload: src(16) | rel(3)<<16 | dlow(9)<<19
__global__ __launch_bounds__(256) void binA_kernel(const int* __restrict__ src,
                                                   const int* __restrict__ dst,
                                                   const int* __restrict__ rel,
                                                   int* __restrict__ cursor98,
                                                   unsigned* __restrict__ coarse) {
    __shared__ int hist[NB1];
    __shared__ int base[NB1];
    int t = threadIdx.x;
    if (t < NB1) hist[t] = 0;
    __syncthreads();
    int e0 = blockIdx.x * CHUNK_A;
    for (int i = t; i < CHUNK_A; i += 256) {
        int e = e0 + i;
        if (e < E_EDGES) atomicAdd(&hist[dst[e] >> 9], 1);
    }
    __syncthreads();
    if (t < NB1) {
        int h = hist[t];
        base[t] = h ? atomicAdd(&cursor98[t], h) : 0;
        hist[t] = 0;
    }
    __syncthreads();
    for (int i = t; i < CHUNK_A; i += 256) {
        int e = e0 + i;
        if (e < E_EDGES) {
            int d = dst[e], b = d >> 9;
            int pos = base[b] + atomicAdd(&hist[b], 1);
            coarse[(size_t)b * BKCAP + pos] = (unsigned)src[e] | ((unsigned)rel[e] << 16)
                                            | ((unsigned)(d & 511) << 19);
        }
    }
}

// Pass B: one block per bucket. LDS (dst,rel) histogram -> invf + per-dst scan
// (begd/cntd) -> exact slot placement.
__global__ __launch_bounds__(512) void binB_kernel(const unsigned* __restrict__ coarse,
                                                   const int* __restrict__ cursor98,
                                                   unsigned* __restrict__ epack,
                                                   int* __restrict__ begd,
                                                   int* __restrict__ cntd,
                                                   float* __restrict__ invf) {
    __shared__ int hist[512 * 8];   // 16 KB: [dlow][rel]
    __shared__ int s[512];
    __shared__ int lcnt[512];
    int b = blockIdx.x, t = threadIdx.x;
    int d0 = b << 9, d = d0 + t;
    #pragma unroll
    for (int r = 0; r < 8; ++r) hist[t * 8 + r] = 0;
    __syncthreads();
    int cnt = cursor98[b];
    const unsigned* cb = coarse + (size_t)b * BKCAP;
    for (int i = t; i < cnt; i += 512) {
        unsigned p = cb[i];
        atomicAdd(&hist[((p >> 19) & 511) * 8 + ((p >> 16) & 7)], 1);
    }
    __syncthreads();
    int c = 0;
    if (d < N_NODES) {
        #pragma unroll
        for (int r = 0; r < 8; ++r) {
            int h = hist[t * 8 + r];
            c += h;
            invf[d * 8 + r] = 1.0f / (float)max(h, 1);
        }
    }
    s[t] = c;
    __syncthreads();
    #pragma unroll
    for (int off = 1; off < 512; off <<= 1) {
        int add = (t >= off) ? s[t - off] : 0;
        __syncthreads();
        s[t] += add;
        __syncthreads();
    }
    int ex = s[t] - c;
    if (d < N_NODES) {
        begd[d] = b * BKCAP + ex;
        cntd[d] = c;
    }
    lcnt[t] = ex;
    __syncthreads();
    for (int i = t; i < cnt; i += 512) {
        unsigned p = cb[i];
        int dlow = (p >> 19) & 511;
        int pos = atomicAdd(&lcnt[dlow], 1);
        epack[(size_t)b * BKCAP + pos] = p & 0x7ffffu;  // src | rel<<16
    }
}

// segagg: 32 lanes per dst node; 4-deep pipelined edge walk (round-13 proven depth).
// Writes yfrag in MFMA fragment order:
//   lane l holds k = b*128 + l*4 + m -> kc=b*4+(l>>3), lhi=(l>>1)&3, j=(l&1)*4+m
__global__ __launch_bounds__(256) void segagg_kernel(const unsigned short* __restrict__ xb,
                                                     const int* __restrict__ begd,
                                                     const int* __restrict__ cntd,
                                                     const float* __restrict__ invf,
                                                     const unsigned* __restrict__ epack,
                                                     const float* __restrict__ coeffs,
                                                     unsigned short* __restrict__ yfrag) {
    int d = blockIdx.x * 8 + (threadIdx.x >> 5);  // grid exact: 50000/8
    int l = threadIdx.x & 31;
    int beg = begd[d];
    int n = cntd[d];
    const unsigned* ep = epack + beg;
    float a0[4] = {}, a1[4] = {}, a2[4] = {}, a3[4] = {};
    int k = 0;
    for (; k + 4 <= n; k += 4) {
        unsigned p0 = ep[k], p1 = ep[k + 1], p2 = ep[k + 2], p3 = ep[k + 3];
        int s0 = p0 & 0xffffu, r0 = p0 >> 16;
        int s1 = p1 & 0xffffu, r1 = p1 >> 16;
        int s2 = p2 & 0xffffu, r2 = p2 >> 16;
        int s3 = p3 & 0xffffu, r3 = p3 >> 16;
        bf16x4 v0 = *(const bf16x4*)&xb[(size_t)s0 * D_IN + l * 4];
        bf16x4 v1 = *(const bf16x4*)&xb[(size_t)s1 * D_IN + l * 4];
        bf16x4 v2 = *(const bf16x4*)&xb[(size_t)s2 * D_IN + l * 4];
        bf16x4 v3 = *(const bf16x4*)&xb[(size_t)s3 * D_IN + l * 4];
        float i0 = invf[d * R_REL + r0];
        float i1 = invf[d * R_REL + r1];
        float i2 = invf[d * R_REL + r2];
        float i3 = invf[d * R_REL + r3];
        float4 cA = *(const float4*)&coeffs[r0 * B_BAS];
        float4 cB = *(const float4*)&coeffs[r1 * B_BAS];
        float4 cC = *(const float4*)&coeffs[r2 * B_BAS];
        float4 cD = *(const float4*)&coeffs[r3 * B_BAS];
        cA.x *= i0; cA.y *= i0; cA.z *= i0; cA.w *= i0;
        cB.x *= i1; cB.y *= i1; cB.z *= i1; cB.w *= i1;
        cC.x *= i2; cC.y *= i2; cC.z *= i2; cC.w *= i2;
        cD.x *= i3; cD.y *= i3; cD.z *= i3; cD.w *= i3;
        #pragma unroll
        for (int j = 0; j < 4; ++j) {
            float x0 = bf2f((unsigned short)v0[j]);
            float x1 = bf2f((unsigned short)v1[j]);
            float x2 = bf2f((unsigned short)v2[j]);
            float x3 = bf2f((unsigned short)v3[j]);
            a0[j] += cA.x * x0; a1[j] += cA.y * x0;
            a2[j] += cA.z * x0; a3[j] += cA.w * x0;
            a0[j] += cB.x * x1; a1[j] += cB.y * x1;
            a2[j] += cB.z * x1; a3[j] += cB.w * x1;
            a0[j] += cC.x * x2; a1[j] += cC.y * x2;
            a2[j] += cC.z * x2; a3[j] += cC.w * x2;
            a0[j] += cD.x * x3; a1[j] += cD.y * x3;
            a2[j] += cD.z * x3; a3[j] += cD.w * x3;
        }
    }
    for (; k < n; ++k) {
        unsigned p0 = ep[k];
        int s0 = p0 & 0xffffu, r0 = p0 >> 16;
        bf16x4 v0 = *(const bf16x4*)&xb[(size_t)s0 * D_IN + l * 4];
        float i0 = invf[d * R_REL + r0];
        float4 cA = *(const float4*)&coeffs[r0 * B_BAS];
        cA.x *= i0; cA.y *= i0; cA.z *= i0; cA.w *= i0;
        #pragma unroll
        for (int j = 0; j < 4; ++j) {
            float x0 = bf2f((unsigned short)v0[j]);
            a0[j] += cA.x * x0; a1[j] += cA.y * x0;
            a2[j] += cA.z * x0; a3[j] += cA.w * x0;
        }
    }
    // fragment-layout stores
    int rt = d >> 4, lrow = d & 15;
    int kc0 = l >> 3, lhi = (l >> 1) & 3, jj = (l & 1) * 4;
    size_t rowbase = (size_t)rt * (NKC * 512);   // shorts per rt = 20*64*8
    #pragma unroll
    for (int b = 0; b < 4; ++b) {
        const float* ab = (b == 0) ? a0 : (b == 1) ? a1 : (b == 2) ? a2 : a3;
        ushort4 o;
        o.x = f2bf(ab[0]); o.y = f2bf(ab[1]); o.z = f2bf(ab[2]); o.w = f2bf(ab[3]);
        size_t addr = rowbase + ((size_t)(b * 4 + kc0) * 64 + lhi * 16 + lrow) * 8 + jj;
        *(ushort4*)&yfrag[addr] = o;
    }
    ushort4 xv = *(const ushort4*)&xb[(size_t)d * D_IN + l * 4];
    size_t addr = rowbase + ((size_t)(16 + kc0) * 64 + lhi * 16 + lrow) * 8 + jj;
    *(ushort4*)&yfrag[addr] = xv;
}

// gemm2: out = relu(A @ Wstack + bias), fragment-layout operands.
// Each wave: 32 rows (2 A-frags) x 64 cols (4 ct) -> 3126 waves.
// Halves per-wave B traffic (250 MB L2 total). Even/odd 2-slot pipeline.
__global__ __launch_bounds__(256) void gemm2_kernel(const unsigned short* __restrict__ yfrag,
                                                    const unsigned short* __restrict__ Wt2f,
                                                    const float* __restrict__ bias,
                                                    float* __restrict__ out) {
    const int w = threadIdx.x >> 6, l = threadIdx.x & 63;
    const int wid = blockIdx.x * 4 + w;
    if (wid >= NRG * 2) return;
    const int g = wid >> 1;
    const int ch = wid & 1;                    // col half: ct base 0 or 4
    const int rt0 = g * 2;
    const int rt1 = (rt0 + 1 < NRT) ? rt0 + 1 : rt0;   // clamp (last group)
    const bool has1 = (rt0 + 1 < NRT);
    const unsigned short* ya0 = yfrag + (size_t)rt0 * (NKC * 512) + l * 8;
    const unsigned short* ya1 = yfrag + (size_t)rt1 * (NKC * 512) + l * 8;
    const unsigned short* wb = Wt2f + (size_t)(ch * 4) * (NKC * 512) + l * 8;
    const int KSTEP = 512;

    f32x4 acc00 = {}, acc01 = {}, acc02 = {}, acc03 = {};
    f32x4 acc10 = {}, acc11 = {}, acc12 = {}, acc13 = {};

#define LA0(kc) (*(const bf16x8*)&ya0[(kc) * KSTEP])
#define LA1(kc) (*(const bf16x8*)&ya1[(kc) * KSTEP])
#define LB(ct, kc) (*(const bf16x8*)&wb[((ct) * NKC + (kc)) * KSTEP])

    bf16x8 aE0 = LA0(0), aE1 = LA1(0);
    bf16x8 bE0 = LB(0, 0), bE1 = LB(1, 0), bE2 = LB(2, 0), bE3 = LB(3, 0);
    bf16x8 aO0 = LA0(1), aO1 = LA1(1);
    bf16x8 bO0 = LB(0, 1), bO1 = LB(1, 1), bO2 = LB(2, 1), bO3 = LB(3, 1);

    #pragma unroll
    for (int kc = 0; kc < NKC; kc += 2) {
        acc00 = __builtin_amdgcn_mfma_f32_16x16x32_bf16(aE0, bE0, acc00, 0, 0, 0);
        acc01 = __builtin_amdgcn_mfma_f32_16x16x32_bf16(aE0, bE1, acc01, 0, 0, 0);
        acc02 = __builtin_amdgcn_mfma_f32_16x16x32_bf16(aE0, bE2, acc02, 0, 0, 0);
        acc03 = __builtin_amdgcn_mfma_f32_16x16x32_bf16(aE0, bE3, acc03, 0, 0, 0);
        acc10 = __builtin_amdgcn_mfma_f32_16x16x32_bf16(aE1, bE0, acc10, 0, 0, 0);
        acc11 = __builtin_amdgcn_mfma_f32_16x16x32_bf16(aE1, bE1, acc11, 0, 0, 0);
        acc12 = __builtin_amdgcn_mfma_f32_16x16x32_bf16(aE1, bE2, acc12, 0, 0, 0);
        acc13 = __builtin_amdgcn_mfma_f32_16x16x32_bf16(aE1, bE3, acc13, 0, 0, 0);
        if (kc + 2 < NKC) {
            aE0 = LA0(kc + 2); aE1 = LA1(kc + 2);
            bE0 = LB(0, kc + 2); bE1 = LB(1, kc + 2);
            bE2 = LB(2, kc + 2); bE3 = LB(3, kc + 2);
        }
        acc00 = __builtin_amdgcn_mfma_f32_16x16x32_bf16(aO0, bO0, acc00, 0, 0, 0);
        acc01 = __builtin_amdgcn_mfma_f32_16x16x32_bf16(aO0, bO1, acc01, 0, 0, 0);
        acc02 = __builtin_amdgcn_mfma_f32_16x16x32_bf16(aO0, bO2, acc02, 0, 0, 0);
        acc03 = __builtin_amdgcn_mfma_f32_16x16x32_bf16(aO0, bO3, acc03, 0, 0, 0);
        acc10 = __builtin_amdgcn_mfma_f32_16x16x32_bf16(aO1, bO0, acc10, 0, 0, 0);
        acc11 = __builtin_amdgcn_mfma_f32_16x16x32_bf16(aO1, bO1, acc11, 0, 0, 0);
        acc12 = __builtin_amdgcn_mfma_f32_16x16x32_bf16(aO1, bO2, acc12, 0, 0, 0);
        acc13 = __builtin_amdgcn_mfma_f32_16x16x32_bf16(aO1, bO3, acc13, 0, 0, 0);
        if (kc + 3 < NKC) {
            aO0 = LA0(kc + 3); aO1 = LA1(kc + 3);
            bO0 = LB(0, kc + 3); bO1 = LB(1, kc + 3);
            bO2 = LB(2, kc + 3); bO3 = LB(3, kc + 3);
        }
    }
#undef LA0
#undef LA1
#undef LB

    // epilogue: C/D layout col=lane&15, row=(lane>>4)*4+i  [m89-verified]
    const int lr = l & 15, lg = l >> 4;
    #pragma unroll
    for (int ct = 0; ct < 4; ++ct) {
        const f32x4& a0 = (ct == 0) ? acc00 : (ct == 1) ? acc01 : (ct == 2) ? acc02 : acc03;
        const f32x4& a1 = (ct == 0) ? acc10 : (ct == 1) ? acc11 : (ct == 2) ? acc12 : acc13;
        int col = (ch * 4 + ct) * 16 + lr;
        float bv = bias[col];
        #pragma unroll
        for (int i2 = 0; i2 < 4; ++i2) {
            int row0 = rt0 * 16 + lg * 4 + i2;
            out[(size_t)row0 * O_OUT + col] = fmaxf(a0[i2] + bv, 0.f);
        }
        if (has1) {
            #pragma unroll
            for (int i2 = 0; i2 < 4; ++i2) {
                int row1 = rt1 * 16 + lg * 4 + i2;
                out[(size_t)row1 * O_OUT + col] = fmaxf(a1[i2] + bv, 0.f);
            }
        }
    }
}

extern "C" void kernel_launch(void* const* d_in, const int* in_sizes, int n_in,
                              void* d_out, int out_size, void* d_ws, size_t ws_size,
                              hipStream_t stream) {
    (void)in_sizes; (void)n_in; (void)out_size; (void)ws_size;
    const float* x       = (const float*)d_in[0];
    const float* basis_v = (const float*)d_in[1];
    const float* coeffs  = (const float*)d_in[2];
    const float* w_loop  = (const float*)d_in[3];
    const float* bias_p  = (const float*)d_in[4];
    const int*   src     = (const int*)d_in[5];
    const int*   dst     = (const int*)d_in[6];
    const int*   rel     = (const int*)d_in[7];
    float* out = (float*)d_out;

    char* ws = (char*)d_ws;
    unsigned short* Wt2f     = (unsigned short*)(ws);             //     163,840 B
    unsigned short* xb       = (unsigned short*)(ws + 163840);    //  12,800,000 B
    float*          invf     = (float*)(ws + 12963840);           //   1,600,000 B
    int*            begd     = (int*)(ws + 14563840);             //     200,000 B
    int*            cntd     = (int*)(ws + 14763840);             //     200,000 B
    int*            cursor98 = (int*)(ws + 14963840);             //       1,024 B
    unsigned*       coarse   = (unsigned*)(ws + 14964864);        //   3,211,264 B
    unsigned*       epack    = (unsigned*)(ws + 18176128);        //   3,211,264 B
    unsigned short* yfrag    = (unsigned short*)(ws + 21387392);  //  64,000,000 B

    prep_kernel<<<NB_CONV + NB_WT, 256, 0, stream>>>(x, xb, basis_v, w_loop, Wt2f, cursor98);
    binA_kernel<<<NBA, 256, 0, stream>>>(src, dst, rel, cursor98, coarse);
    binB_kernel<<<NB1, 512, 0, stream>>>(coarse, cursor98, epack, begd, cntd, invf);
    segagg_kernel<<<N_NODES / 8, 256, 0, stream>>>(xb, begd, cntd, invf, epack, coeffs, yfrag);
    gemm2_kernel<<<(NRG * 2 + 3) / 4, 256, 0, stream>>>(yfrag, Wt2f, bias_p, out);
}